// Round 1
// baseline (311.257 us; speedup 1.0000x reference)
//
#include <hip/hip_runtime.h>

#define CLIPV 100000.0f

__device__ __forceinline__ float fexp2(float x) { return __builtin_amdgcn_exp2f(x); }
__device__ __forceinline__ float frcp(float x)  { return __builtin_amdgcn_rcpf(x); }

struct PP {
    float smax_s, qmax_s, k10, inv_smax, ddf5, tmax3, cw, Kc, cf;
};

// soilbucket terms at state s1 (pet-independent parts + et coefficient).
// qq = qsurf + qsub (total s1 drain except et), c_et: et = c_et * pet,
// o0 = qsurf + qst, o1 = qgr.
__device__ __forceinline__ void soilb(float s1, const PP& P,
                                      float& qq, float& c_et, float& o0, float& o1)
{
    const float NL = -14.426950408889634f;  // -10 * log2(e)
    float d   = s1 - P.smax_s;
    float eo  = fminf(fexp2(NL * d), 1e30f);   // exp(-10(s1-smax)), clamped (avoid 0*inf)
    float ep  = fexp2(NL * s1);                // exp(-10 s1), s1 >= -O(2) so finite
    float hpo = frcp((1.0f + ep) * (1.0f + eo));  // h_pos*h_over
    float hpu = eo * hpo;                         // h_pos*h_under
    float e   = fexp2(P.cf * d);               // exp(-f10*(smax-s1))
    float qsub  = P.qmax_s * fmaf(hpu, e, hpo);
    float qsurf = hpo * d;
    float qst = qsub * P.k10;
    o0 = qsurf + qst;
    o1 = qsub - qst;          // qgr = qsub*(1-k)
    qq = qsurf + qsub;        // qsurf + qst + qgr
    c_et = fmaf(hpu * s1, P.inv_smax, hpo);
}

__device__ __forceinline__ void one_step(float p, float tm, float dl, const PP& P,
                                         float& s0, float& s1, float& qq, float& c_et,
                                         float& o0, float& o1)
{
    const float NL = -14.426950408889634f;
    // pet = 29.8*24*0.611 * dayl * exp(17.3*tm/(tm+237.3)) / (tm+273.2)
    float r1  = frcp(tm + 237.3f);
    float e1  = fexp2(24.958624207f * tm * r1);   // exp(...) via exp2, 17.3*log2e
    float r2  = frcp(tm + 273.2f);
    float pet = 436.98720f * dl * e1 * r2;
    // rain/snow split: w = heaviside(tm - tmin_s)
    float ew  = fexp2(fmaf(NL, tm, P.cw));
    float w   = frcp(1.0f + ew);
    float prain = w * p;
    float psnow = p - prain;                      // (1-w)*p exactly
    // melt gate shares ew: e_g = exp(-10(tm - tmax3)) = ew * Kc
    float eg  = ew * P.Kc;                        // overflow -> inf -> gate 0 (correct limit)
    float es0 = fexp2(NL * s0);                   // s0 >= 0 so <= 1
    float hg  = frcp((1.0f + es0) * (1.0f + eg)); // heaviside(s0)*heaviside(tm-tmax3)
    float m   = hg * fminf(s0, P.ddf5 * (tm - P.tmax3));
    float et  = c_et * pet;
    float ds0 = psnow - m;
    float ds1 = prain + m - et - qq;
    s0 += fminf(fmaxf(ds0, -CLIPV), CLIPV);
    s1 += fminf(fmaxf(ds1, -CLIPV), CLIPV);
    // soilbucket on the UPDATED s1: gives this step's outputs AND next step's drains
    soilb(s1, P, qq, c_et, o0, o1);
}

extern "C" __global__ void __launch_bounds__(64)
prnn_kernel(const float* __restrict__ inp,
            const float* __restrict__ fpar,  const float* __restrict__ smaxp,
            const float* __restrict__ qmaxp, const float* __restrict__ ddfp,
            const float* __restrict__ tminp, const float* __restrict__ tmaxp,
            const float* __restrict__ kp,
            float* __restrict__ out)
{
    const int b = blockIdx.x * 64 + threadIdx.x;

    PP P;
    float f10   = fpar[0] * 0.1f;
    P.smax_s    = smaxp[0] * 1500.0f;
    P.qmax_s    = qmaxp[0] * 50.0f;
    P.ddf5      = ddfp[0] * 5.0f;
    float tmin_s = tminp[0] * -3.0f;
    P.tmax3     = tmaxp[0] * 3.0f;
    P.k10       = kp[0] * 0.1f;
    P.inv_smax  = 1.0f / P.smax_s;
    P.cw        = 14.426950408889634f * tmin_s;
    P.Kc        = fexp2(14.426950408889634f * (P.tmax3 - tmin_s));
    P.cf        = 1.4426950408889634f * f10;

    // per-thread row: T*3 = 3072 floats = 768 float4; out row: T*2 = 2048 floats = 512 float4
    const float4* __restrict__ row  = (const float4*)(inp) + (size_t)b * 768;
    float4* __restrict__       orow = (float4*)(out) + (size_t)b * 512;

    float s0 = 0.0f, s1 = 0.0f, qq, c_et, t0, t1;
    soilb(0.0f, P, qq, c_et, t0, t1);   // initial coefficients at s1=0

    // software pipeline: chunks of 4 steps (3 float4 each), depth 2 (8 steps ahead)
    float4 A0 = row[0], B0 = row[1], C0 = row[2];
    float4 A1 = row[3], B1 = row[4], C1 = row[5];

    for (int j = 0; j < 256; j += 2) {
        int j2 = (j + 2 < 256) ? j + 2 : 254;
        float4 nA0 = row[3*j2], nB0 = row[3*j2+1], nC0 = row[3*j2+2];
        {
            float o0,o1,o2,o3,o4,o5,o6,o7;
            one_step(A0.x, A0.y, A0.z, P, s0,s1,qq,c_et, o0,o1);
            one_step(A0.w, B0.x, B0.y, P, s0,s1,qq,c_et, o2,o3);
            one_step(B0.z, B0.w, C0.x, P, s0,s1,qq,c_et, o4,o5);
            one_step(C0.y, C0.z, C0.w, P, s0,s1,qq,c_et, o6,o7);
            orow[2*j]   = make_float4(o0,o1,o2,o3);
            orow[2*j+1] = make_float4(o4,o5,o6,o7);
        }
        int j3 = (j + 3 < 256) ? j + 3 : 255;
        float4 nA1 = row[3*j3], nB1 = row[3*j3+1], nC1 = row[3*j3+2];
        {
            float o0,o1,o2,o3,o4,o5,o6,o7;
            one_step(A1.x, A1.y, A1.z, P, s0,s1,qq,c_et, o0,o1);
            one_step(A1.w, B1.x, B1.y, P, s0,s1,qq,c_et, o2,o3);
            one_step(B1.z, B1.w, C1.x, P, s0,s1,qq,c_et, o4,o5);
            one_step(C1.y, C1.z, C1.w, P, s0,s1,qq,c_et, o6,o7);
            orow[2*j+2] = make_float4(o0,o1,o2,o3);
            orow[2*j+3] = make_float4(o4,o5,o6,o7);
        }
        A0 = nA0; B0 = nB0; C0 = nC0;
        A1 = nA1; B1 = nB1; C1 = nC1;
    }
}

extern "C" void kernel_launch(void* const* d_in, const int* in_sizes, int n_in,
                              void* d_out, int out_size, void* d_ws, size_t ws_size,
                              hipStream_t stream) {
    const float* inp = (const float*)d_in[0];
    const int B = in_sizes[0] / 3072;      // T=1024, 3 features
    prnn_kernel<<<B / 64, 64, 0, stream>>>(
        inp,
        (const float*)d_in[1],  // f
        (const float*)d_in[2],  // smax
        (const float*)d_in[3],  // qmax
        (const float*)d_in[4],  // ddf
        (const float*)d_in[5],  // tmin
        (const float*)d_in[6],  // tmax
        (const float*)d_in[7],  // k
        (float*)d_out);
}